// Round 21
// baseline (601.661 us; speedup 1.0000x reference)
//
#include <hip/hip_runtime.h>
#include <hip/hip_bf16.h>

#define N_NODES 100000
#define N_EDGES 1600000
#define HDIM    128
#define NLAYER  6
#define NGRAPH  128
#define NCLASS  10
#define BN_EPS  1e-5f

#define POOL_SPLIT 16

#define NBUCK   196          // buckets of 512 nodes (dst >> 9)
#define BSH     9
#define KC_BLOCKS 250
#define KC_CHUNK  6400       // 250 * 6400 = 1.6M edges
#define LCOL_CAP  10240
#define QW      25000u       // src quartile width

#define GBM 64
#define NBLK_G ((N_NODES + GBM - 1) / GBM)                     // 1563

typedef __attribute__((ext_vector_type(8))) short short8v;
typedef __attribute__((ext_vector_type(4))) float f32x4;
typedef __attribute__((ext_vector_type(2))) float f32x2;
typedef __attribute__((ext_vector_type(4))) int int4v;
typedef __attribute__((ext_vector_type(2))) int int2v;

__device__ __forceinline__ float b2f(unsigned short h) {
    return __uint_as_float(((unsigned int)h) << 16);
}
__device__ __forceinline__ unsigned short f2b(float f) {
    unsigned int u = __float_as_uint(f);
    u += 0x7FFF + ((u >> 16) & 1);          // RNE
    return (unsigned short)(u >> 16);
}
__device__ __forceinline__ unsigned char f2f8(float f) {
    unsigned int u = __builtin_amdgcn_cvt_pk_fp8_f32(f, f, 0, false);
    return (unsigned char)(u & 0xff);
}
__device__ __forceinline__ void gl_lds16(const void* g, void* l) {
    __builtin_amdgcn_global_load_lds((const __attribute__((address_space(1))) unsigned int*)g,
                                     (__attribute__((address_space(3))) unsigned int*)l,
                                     16, 0, 0);
}
// 8 fp8 (pre-BN H) -> bn+relu -> 8 bf16
__device__ __forceinline__ short8v bn_pack8(int2v rv8, const float* __restrict__ scsh,
                                            int c0) {
    short8v o;
#pragma unroll
    for (int w = 0; w < 2; ++w) {
        unsigned int u = (unsigned int)rv8[w];
        f32x2 lo = __builtin_amdgcn_cvt_pk_f32_fp8(u, false);
        f32x2 hi = __builtin_amdgcn_cvt_pk_f32_fp8(u, true);
        float f[4] = { lo[0], lo[1], hi[0], hi[1] };
#pragma unroll
        for (int j = 0; j < 4; ++j) {
            int c = c0 + w * 4 + j;
            o[w * 4 + j] = (short)f2b(fmaxf(0.f, f[j] * scsh[c] + scsh[HDIM + c]));
        }
    }
    return o;
}

// ---------------- CSR build v4: bucketed radix, per-node lists sorted by src quartile ----------------

__global__ void __launch_bounds__(256) k_hist(const int* __restrict__ dst,
                                              int* __restrict__ bcnt) {
    __shared__ int h[NBUCK];
    for (int i = threadIdx.x; i < NBUCK; i += 256) h[i] = 0;
    __syncthreads();
    const int4v* d4 = (const int4v*)dst;
    int base = blockIdx.x * (KC_CHUNK / 4);
    for (int i = threadIdx.x; i < KC_CHUNK / 4; i += 256) {
        int4v d = __builtin_nontemporal_load(d4 + base + i);
        atomicAdd(&h[d[0] >> BSH], 1);
        atomicAdd(&h[d[1] >> BSH], 1);
        atomicAdd(&h[d[2] >> BSH], 1);
        atomicAdd(&h[d[3] >> BSH], 1);
    }
    __syncthreads();
    for (int i = threadIdx.x; i < NBUCK; i += 256)
        if (h[i]) atomicAdd(&bcnt[i], h[i]);
}

__global__ void k_bscan(const int* __restrict__ bcnt, int* __restrict__ boff,
                        int* __restrict__ bcur, int* __restrict__ row_off) {
    if (threadIdx.x == 0 && blockIdx.x == 0) {
        int acc = 0;
        for (int i = 0; i < NBUCK; ++i) {
            boff[i] = acc; bcur[i] = acc; acc += bcnt[i];
        }
        boff[NBUCK] = acc;
        row_off[N_NODES] = N_EDGES;
    }
}

__global__ void __launch_bounds__(256) k_part(const int* __restrict__ src,
                                              const int* __restrict__ dst,
                                              int* __restrict__ bcur,
                                              int2v* __restrict__ P) {
    __shared__ int h[NBUCK];
    __shared__ int gbase[NBUCK];
    for (int i = threadIdx.x; i < NBUCK; i += 256) h[i] = 0;
    __syncthreads();
    const int4v* d4 = (const int4v*)dst;
    const int4v* s4 = (const int4v*)src;
    const int base = blockIdx.x * (KC_CHUNK / 4);
    for (int i = threadIdx.x; i < KC_CHUNK / 4; i += 256) {
        int4v d = __builtin_nontemporal_load(d4 + base + i);
        atomicAdd(&h[d[0] >> BSH], 1);
        atomicAdd(&h[d[1] >> BSH], 1);
        atomicAdd(&h[d[2] >> BSH], 1);
        atomicAdd(&h[d[3] >> BSH], 1);
    }
    __syncthreads();
    for (int i = threadIdx.x; i < NBUCK; i += 256) {
        int c = h[i];
        gbase[i] = c ? atomicAdd(&bcur[i], c) : 0;
        h[i] = 0;
    }
    __syncthreads();
    for (int i = threadIdx.x; i < KC_CHUNK / 4; i += 256) {
        int4v d = __builtin_nontemporal_load(d4 + base + i);
        int4v s = __builtin_nontemporal_load(s4 + base + i);
#pragma unroll
        for (int k = 0; k < 4; ++k) {
            int b = d[k] >> BSH;
            int pos = gbase[b] + atomicAdd(&h[b], 1);
            int2v pr; pr[0] = s[k]; pr[1] = d[k];
            P[pos] = pr;
        }
    }
}

__global__ void __launch_bounds__(1024) k_bucket(const int2v* __restrict__ P,
                                                 const int* __restrict__ boff,
                                                 int* __restrict__ row_off,
                                                 int* __restrict__ col) {
    __shared__ int ldeg[2048];
    __shared__ int lcur[2048];
    __shared__ int lcol[LCOL_CAP];
    const int tid = threadIdx.x;
    const int b = blockIdx.x;
    const int pbeg = boff[b], pend = boff[b + 1];
    const int nE = pend - pbeg;
    const int n0 = b << BSH;
    for (int i = tid; i < 2048; i += 1024) ldeg[i] = 0;
    __syncthreads();
    for (int i = tid; i < nE; i += 1024) {
        int2v pr = P[pbeg + i];
        int q = (int)((unsigned)pr[0] / QW);
        atomicAdd(&ldeg[((pr[1] - n0) << 2) + q], 1);
    }
    __syncthreads();
    int a0 = ldeg[2 * tid];
    int a1 = ldeg[2 * tid + 1];
    lcur[tid] = a0 + a1;
    __syncthreads();
    for (int off = 1; off < 1024; off <<= 1) {
        int t = (tid >= off) ? lcur[tid - off] : 0;
        __syncthreads();
        lcur[tid] += t;
        __syncthreads();
    }
    int basex = (tid > 0) ? lcur[tid - 1] : 0;
    __syncthreads();
    ldeg[2 * tid] = basex;
    ldeg[2 * tid + 1] = basex + a0;
    __syncthreads();
    for (int i = tid; i < 2048; i += 1024) lcur[i] = ldeg[i];
    if (tid < 512) {
        int node = n0 + tid;
        if (node < N_NODES) row_off[node] = pbeg + ldeg[tid << 2];
    }
    __syncthreads();
    for (int i = tid; i < nE; i += 1024) {
        int2v pr = P[pbeg + i];
        int q = (int)((unsigned)pr[0] / QW);
        int pos = atomicAdd(&lcur[((pr[1] - n0) << 2) + q], 1);
        if (pos < LCOL_CAP) lcol[pos] = pr[0];
    }
    __syncthreads();
    for (int i = tid; i < nE; i += 1024) col[pbeg + i] = lcol[i];
}

// ---------------- one-time converts ----------------

__global__ void __launch_bounds__(256) k_cvt_x(const float* __restrict__ x,
                                               unsigned short* __restrict__ Xb,
                                               unsigned int* __restrict__ X8) {
    int idx = blockIdx.x * 256 + threadIdx.x;
    f32x4 v = __builtin_nontemporal_load(((const f32x4*)x) + idx);
    ushort4 o = { f2b(v[0]), f2b(v[1]), f2b(v[2]), f2b(v[3]) };
    ((ushort4*)Xb)[idx] = o;
    unsigned int d = 0;
    d = __builtin_amdgcn_cvt_pk_fp8_f32(v[0], v[1], d, false);
    d = __builtin_amdgcn_cvt_pk_fp8_f32(v[2], v[3], d, true);
    X8[idx] = d;
}

__global__ void __launch_bounds__(256) k_cvt_w(const float* __restrict__ Wl,
                                               const float* __restrict__ Wr,
                                               unsigned short* __restrict__ Wtb) {
    int idx = blockIdx.x * 256 + threadIdx.x;
    int kk = idx & 255;
    int n  = (idx >> 8) & 127;
    int l  = idx >> 15;
    float v = (kk < HDIM) ? Wl[l * HDIM * HDIM + kk * HDIM + n]
                          : Wr[l * HDIM * HDIM + (kk - HDIM) * HDIM + n];
    Wtb[idx] = f2b(v);
}

// X8 = fp8(relu(bn(H8)))  (H8 is pre-BN fp8)
__global__ void __launch_bounds__(256) k_bnx8(const unsigned char* __restrict__ H8,
                                              const float* __restrict__ scsh,
                                              int2v* __restrict__ X8) {
    int idx = blockIdx.x * 256 + threadIdx.x;
    int c8 = (idx & 15) * 8;
    int2v v = ((const int2v*)H8)[idx];
    float f[8];
#pragma unroll
    for (int w = 0; w < 2; ++w) {
        unsigned int u = (unsigned int)v[w];
        f32x2 lo = __builtin_amdgcn_cvt_pk_f32_fp8(u, false);
        f32x2 hi = __builtin_amdgcn_cvt_pk_f32_fp8(u, true);
        f[w * 4 + 0] = lo[0]; f[w * 4 + 1] = lo[1];
        f[w * 4 + 2] = hi[0]; f[w * 4 + 3] = hi[1];
    }
#pragma unroll
    for (int j = 0; j < 8; ++j)
        f[j] = fmaxf(0.f, f[j] * scsh[c8 + j] + scsh[HDIM + c8 + j]);
    unsigned int d0 = 0, d1 = 0;
    d0 = __builtin_amdgcn_cvt_pk_fp8_f32(f[0], f[1], d0, false);
    d0 = __builtin_amdgcn_cvt_pk_fp8_f32(f[2], f[3], d0, true);
    d1 = __builtin_amdgcn_cvt_pk_fp8_f32(f[4], f[5], d1, false);
    d1 = __builtin_amdgcn_cvt_pk_fp8_f32(f[6], f[7], d1, true);
    int2v o; o[0] = (int)d0; o[1] = (int)d1;
    X8[idx] = o;
}

// ---------------- fused fp8-gather + GEMM + BN-stat partials ----------------
// 256 thr = 4 waves (1m x 4n), 64 rows/block, LDS 24KB (A dbuf 2x4K @0 | W dbuf 2x8K @8K).
// Small blocks -> ~6 blocks/CU resident -> gather latency hidden by TLP.
// Swizzle g(r)=(r>>1)&3; LDS[r][j^g(r)] = G[r][j].

template<bool BN>
__global__ void __launch_bounds__(256) k_fused(const unsigned char* __restrict__ X8,
                                               const void* __restrict__ Hsrc,
                                               const float* __restrict__ scsh,
                                               const int* __restrict__ row_off,
                                               const int* __restrict__ col,
                                               const unsigned short* __restrict__ Wtb,
                                               const float* __restrict__ bl,
                                               unsigned char* __restrict__ H8out,
                                               float* __restrict__ pstat) {
    __shared__ __align__(16) char smem[24576];
    __shared__ int sro[65];
    const int tid  = threadIdx.x;
    const int bm   = blockIdx.x * GBM;
    const int wv   = tid >> 6;                 // 0..3 ; wave owns cols [wv*32, wv*32+32)
    const int lane = tid & 63;
    const int li   = lane & 15, hi = lane >> 4;
    const int rr   = tid >> 2, sk = tid & 3;   // rr 0..63
    const int swz  = ((sk ^ ((rr >> 1) & 3)) << 4);

    // prefetch W step 0 into buf0 (2 passes of 256 threads; g(q*64+rr)==g(rr))
#pragma unroll
    for (int q = 0; q < 2; ++q) {
        int n = q * 64 + rr;
        gl_lds16((const char*)(Wtb + (size_t)n * 256) + swz,
                 smem + 8192 + q * 4096 + wv * 1024);
    }

    // stage row offsets + col indices (lcol overlays A dbuf region, 2048 ints)
    int* lcol = (int*)smem;
    if (tid <= 64) {
        int ii = bm + tid; if (ii > N_NODES) ii = N_NODES;
        sro[tid] = row_off[ii];
    }
    __syncthreads();
    const int s0 = sro[0];
    const int nEb = sro[64] - s0;
    const bool fits = (nEb <= 2048);
    if (fits) for (int i = tid; i < nEb; i += 256) lcol[i] = col[s0 + i];
    __syncthreads();

    // ---- gather phase: node bm+rr, fp8 channels [32sk, 32sk+32) ----
    const int s = sro[rr] - s0, e = sro[rr + 1] - s0;
    const int* cp = fits ? lcol : (col + s0);
    const int c32 = sk * 32;
    f32x2 a2[16] = {};
    auto accum16 = [&](int4v v, int base) {
#pragma unroll
        for (int q = 0; q < 4; ++q) {
            unsigned int w = (unsigned int)v[q];
            a2[base + 2 * q]     += __builtin_amdgcn_cvt_pk_f32_fp8(w, false);
            a2[base + 2 * q + 1] += __builtin_amdgcn_cvt_pk_f32_fp8(w, true);
        }
    };
    int p = s;
    for (; p + 4 <= e; p += 4) {
        int nbx[4];
#pragma unroll
        for (int j = 0; j < 4; ++j) nbx[j] = cp[p + j];
        int4v v0[4], v1[4];
#pragma unroll
        for (int j = 0; j < 4; ++j) {
            const unsigned char* rowp = X8 + (size_t)nbx[j] * HDIM + c32;
            v0[j] = *(const int4v*)rowp;
            v1[j] = *(const int4v*)(rowp + 16);
        }
#pragma unroll
        for (int j = 0; j < 4; ++j) { accum16(v0[j], 0); accum16(v1[j], 8); }
    }
    for (; p < e; ++p) {
        const unsigned char* rowp = X8 + (size_t)cp[p] * HDIM + c32;
        accum16(*(const int4v*)rowp, 0);
        accum16(*(const int4v*)(rowp + 16), 8);
    }
    const float wgt = (e > s) ? 1.0f / (float)(e - s) : 0.f;
    short8v aggout[4];
#pragma unroll
    for (int j = 0; j < 4; ++j)
#pragma unroll
        for (int t = 0; t < 8; ++t)
            aggout[j][t] = (short)f2b(a2[j * 4 + (t >> 1)][t & 1] * wgt);

    __syncthreads();                       // lcol reads done; safe to overwrite A region
    if (sk == 0) {                         // write A tile for step 0 into buf0
#pragma unroll
        for (int j = 0; j < 4; ++j)
            *(short8v*)(smem + rr * 64 + ((j ^ ((rr >> 1) & 3)) << 4)) = aggout[j];
    }
    __syncthreads();

    // ---- K-loop ----
    f32x4 acc[4][2] = {};
    int buf = 0;
    for (int step = 0; step < 8; ++step) {
        char* curA = smem + buf * 4096;
        char* curW = smem + 8192 + buf * 8192;
        char* nxtA = smem + (buf ^ 1) * 4096;
        const int ns = step + 1;
        short8v rv16;
        int2v rv8;
        int c0 = 0;
        bool regstage = false;
        if (step < 7) {
#pragma unroll
            for (int q = 0; q < 2; ++q) {
                int n = q * 64 + rr;
                gl_lds16((const char*)(Wtb + (size_t)n * 256 + ns * 32) + swz,
                         smem + 8192 + (buf ^ 1) * 8192 + q * 4096 + wv * 1024);
            }
            if (ns >= 4) {
                regstage = true;
                c0 = (ns - 4) * 32 + sk * 8;
                int row = bm + rr; if (row >= N_NODES) row = N_NODES - 1;
                if (BN) {
                    rv8 = *(const int2v*)((const unsigned char*)Hsrc +
                                          (size_t)row * HDIM + c0);
                } else {
                    rv16 = *(const short8v*)((const unsigned short*)Hsrc +
                                             (size_t)row * HDIM + c0);
                }
            }
        }

        short8v afr[4], bfr[2];
#pragma unroll
        for (int m = 0; m < 4; ++m) {
            int r = m * 16 + li;
            afr[m] = *(const short8v*)(curA + r * 64 + ((hi ^ ((r >> 1) & 3)) << 4));
        }
#pragma unroll
        for (int nf = 0; nf < 2; ++nf) {
            int n = wv * 32 + nf * 16 + li;
            bfr[nf] = *(const short8v*)(curW + n * 64 + ((hi ^ ((n >> 1) & 3)) << 4));
        }
#pragma unroll
        for (int m = 0; m < 4; ++m)
#pragma unroll
            for (int nf = 0; nf < 2; ++nf)
                acc[m][nf] = __builtin_amdgcn_mfma_f32_16x16x32_bf16(afr[m], bfr[nf],
                                                                     acc[m][nf], 0, 0, 0);

        if (step < 7) {
            if (ns < 4) {
                if (sk == ns) {
#pragma unroll
                    for (int j = 0; j < 4; ++j)
                        *(short8v*)(nxtA + rr * 64 + ((j ^ ((rr >> 1) & 3)) << 4)) = aggout[j];
                }
            } else if (regstage) {
                short8v ov;
                if (BN) ov = bn_pack8(rv8, scsh, c0);
                else    ov = rv16;
                *(short8v*)(nxtA + rr * 64 + swz) = ov;
            }
        }
        __syncthreads();
        buf ^= 1;
    }

    // ---- epilogue: bias, fp8 H write, per-wave BN-stat partials (no LDS stage) ----
#pragma unroll
    for (int nf = 0; nf < 2; ++nf) {
        int c = wv * 32 + nf * 16 + li;
        float bb = bl[c];
        float ls = 0.f, lq = 0.f;
#pragma unroll
        for (int m = 0; m < 4; ++m) {
            int row0 = bm + m * 16 + hi * 4;
#pragma unroll
            for (int j = 0; j < 4; ++j) {
                int row = row0 + j;
                if (row < N_NODES) {
                    float v = acc[m][nf][j] + bb;
                    H8out[(size_t)row * HDIM + c] = f2f8(v);
                    ls += v; lq += v * v;
                }
            }
        }
        ls += __shfl_xor(ls, 16); ls += __shfl_xor(ls, 32);
        lq += __shfl_xor(lq, 16); lq += __shfl_xor(lq, 32);
        if (hi == 0) {
            pstat[blockIdx.x * 256 + c] = ls;
            pstat[blockIdx.x * 256 + 128 + c] = lq;
        }
    }
}

// ---------------- BN stats reduction (2 dispatches, parallel) ----------------

__global__ void __launch_bounds__(256) k_red1(const float* __restrict__ pstat,
                                              float* __restrict__ red32) {
    int c = threadIdx.x, b = blockIdx.x;
    float s = 0.f;
    for (int r = b; r < NBLK_G; r += 32) s += pstat[r * 256 + c];
    red32[b * 256 + c] = s;
}

__global__ void __launch_bounds__(128) k_stats_final(const float* __restrict__ red32,
                                                     const float* __restrict__ gamma,
                                                     const float* __restrict__ beta,
                                                     float* __restrict__ scsh) {
    int c = threadIdx.x;
    float s = 0.f, q = 0.f;
    for (int r = 0; r < 32; ++r) { s += red32[r * 256 + c]; q += red32[r * 256 + 128 + c]; }
    float mu = s / (float)N_NODES;
    float var = q / (float)N_NODES - mu * mu;
    float rs = rsqrtf(var + BN_EPS);
    float sc = gamma[c] * rs;
    scsh[c] = sc;
    scsh[HDIM + c] = beta[c] - mu * sc;
}

// ---------------- pooling + classifier ----------------

__global__ void k_gbound(const int* __restrict__ batch, int* __restrict__ gb) {
    int t = blockIdx.x * 64 + threadIdx.x;
    if (t > NGRAPH) return;
    int lo = 0, hi = N_NODES;
    while (lo < hi) { int mid = (lo + hi) >> 1; if (batch[mid] < t) lo = mid + 1; else hi = mid; }
    gb[t] = lo;
}

__global__ void __launch_bounds__(128) k_pool_part(const unsigned char* __restrict__ H8,
                                                   const float* __restrict__ scsh,
                                                   const int* __restrict__ gb,
                                                   float* __restrict__ ppart) {
    int g = blockIdx.x, sp = blockIdx.y;
    int c = threadIdx.x;
    float sc = scsh[c], sh = scsh[HDIM + c];
    int s = gb[g], e = gb[g + 1];
    float acc = 0.f;
    for (int i = s + sp; i < e; i += POOL_SPLIT) {
        unsigned int u = (unsigned int)H8[(size_t)i * HDIM + c];
        f32x2 t = __builtin_amdgcn_cvt_pk_f32_fp8(u, false);
        acc += fmaxf(0.f, t[0] * sc + sh);
    }
    ppart[(g * POOL_SPLIT + sp) * HDIM + c] = acc;
}

__global__ void __launch_bounds__(128) k_pool_final(const int* __restrict__ gb,
                                                    const float* __restrict__ ppart,
                                                    float* __restrict__ pooled) {
    int g = blockIdx.x, c = threadIdx.x;
    float s = 0.f;
    for (int sp = 0; sp < POOL_SPLIT; ++sp) s += ppart[(g * POOL_SPLIT + sp) * HDIM + c];
    int cnt = gb[g + 1] - gb[g]; if (cnt < 1) cnt = 1;
    pooled[g * HDIM + c] = s / (float)cnt;
}

__global__ void __launch_bounds__(128) k_lin(const float* __restrict__ pooled,
                                             const float* __restrict__ W,
                                             const float* __restrict__ bvec,
                                             float* __restrict__ out) {
    __shared__ float p[HDIM];
    int g = blockIdx.x, t = threadIdx.x;
    p[t] = pooled[g * HDIM + t];
    __syncthreads();
    if (t < NCLASS) {
        float acc = bvec[t];
        for (int k = 0; k < HDIM; ++k) acc += p[k] * W[k * NCLASS + t];
        out[g * NCLASS + t] = acc;
    }
}

// ---------------- launch ----------------

extern "C" void kernel_launch(void* const* d_in, const int* in_sizes, int n_in,
                              void* d_out, int out_size, void* d_ws, size_t ws_size,
                              hipStream_t stream) {
    const float* x     = (const float*)d_in[0];
    const int*   eidx  = (const int*)d_in[1];
    const int*   batch = (const int*)d_in[2];
    const float* Wl    = (const float*)d_in[3];
    const float* bl    = (const float*)d_in[4];
    const float* Wr    = (const float*)d_in[5];
    const float* gamma = (const float*)d_in[6];
    const float* beta  = (const float*)d_in[7];
    const float* linW  = (const float*)d_in[8];
    const float* linb  = (const float*)d_in[9];
    float* out = (float*)d_out;

    const int* src = eidx;
    const int* dst = eidx + N_EDGES;

    char* p = (char*)d_ws;
    auto alloc = [&](size_t bytes) { char* r = p; p += (bytes + 255) & ~(size_t)255; return r; };
    unsigned short* Xb   = (unsigned short*)alloc((size_t)N_NODES * HDIM * 2);
    unsigned char*  X8   = (unsigned char*)alloc((size_t)N_NODES * HDIM);
    unsigned char*  H8A  = (unsigned char*)alloc((size_t)N_NODES * HDIM);
    unsigned char*  H8B  = (unsigned char*)alloc((size_t)N_NODES * HDIM);
    unsigned short* Wtb  = (unsigned short*)alloc((size_t)NLAYER * 2 * HDIM * HDIM * 2);
    int*   row_off = (int*)alloc((N_NODES + 2) * 4);
    int*   col     = (int*)alloc((size_t)N_EDGES * 4);
    int2v* P       = (int2v*)alloc((size_t)N_EDGES * 8);
    int*   bcnt    = (int*)alloc(NBUCK * 4);
    int*   boff    = (int*)alloc((NBUCK + 1) * 4);
    int*   bcur    = (int*)alloc(NBUCK * 4);
    int*   gb      = (int*)alloc((NGRAPH + 2) * 4);
    float* pstat   = (float*)alloc((size_t)NBLK_G * 256 * 4);
    float* red32   = (float*)alloc(32 * 256 * 4);
    float* scsh    = (float*)alloc(2 * HDIM * 4);
    float* ppart   = (float*)alloc((size_t)NGRAPH * POOL_SPLIT * HDIM * 4);
    float* pooled  = (float*)alloc(NGRAPH * HDIM * 4);

    // ---- CSR build v4 ----
    hipMemsetAsync(bcnt, 0, NBUCK * sizeof(int), stream);
    k_hist<<<KC_BLOCKS, 256, 0, stream>>>(dst, bcnt);
    k_bscan<<<1, 64, 0, stream>>>(bcnt, boff, bcur, row_off);
    k_part<<<KC_BLOCKS, 256, 0, stream>>>(src, dst, bcur, P);
    k_bucket<<<NBUCK, 1024, 0, stream>>>(P, boff, row_off, col);

    // ---- one-time converts ----
    k_cvt_x<<<N_NODES * HDIM / 4 / 256, 256, 0, stream>>>(x, Xb, (unsigned int*)X8);
    k_cvt_w<<<NLAYER * 2 * HDIM * HDIM / 256, 256, 0, stream>>>(Wl, Wr, Wtb);
    k_gbound<<<3, 64, 0, stream>>>(batch, gb);

    // ---- layer 0 (root operand = bf16 Xb) ----
    k_fused<false><<<NBLK_G, 256, 0, stream>>>(X8, Xb, scsh, row_off, col,
                                               Wtb, bl, H8A, pstat);
    k_red1<<<32, 256, 0, stream>>>(pstat, red32);
    k_stats_final<<<1, 128, 0, stream>>>(red32, gamma, beta, scsh);

    // ---- layers 1..5 (root operand = fp8 H8prev + in-register BN) ----
    unsigned char* Hcur = H8A;
    for (int l = 1; l < NLAYER; ++l) {
        unsigned char* Hout = (l & 1) ? H8B : H8A;
        k_bnx8<<<N_NODES * HDIM / 8 / 256, 256, 0, stream>>>(Hcur, scsh, (int2v*)X8);
        k_fused<true><<<NBLK_G, 256, 0, stream>>>(
            X8, Hcur, scsh, row_off, col, Wtb + (size_t)l * 2 * HDIM * HDIM,
            bl + (size_t)l * HDIM, Hout, pstat);
        k_red1<<<32, 256, 0, stream>>>(pstat, red32);
        k_stats_final<<<1, 128, 0, stream>>>(red32, gamma + (size_t)l * HDIM,
                                             beta + (size_t)l * HDIM, scsh);
        Hcur = Hout;
    }

    // ---- pool + classifier ----
    k_pool_part<<<dim3(NGRAPH, POOL_SPLIT), 128, 0, stream>>>(Hcur, scsh, gb, ppart);
    k_pool_final<<<NGRAPH, 128, 0, stream>>>(gb, ppart, pooled);
    k_lin<<<NGRAPH, 128, 0, stream>>>(pooled, linW, linb, out);
}

// Round 22
// 549.286 us; speedup vs baseline: 1.0954x; 1.0954x over previous
//
#include <hip/hip_runtime.h>
#include <hip/hip_bf16.h>

#define N_NODES 100000
#define N_EDGES 1600000
#define HDIM    128
#define NLAYER  6
#define NGRAPH  128
#define NCLASS  10
#define BN_EPS  1e-5f

#define POOL_SPLIT 16

#define NBUCK   196          // buckets of 512 nodes (dst >> 9)
#define BSH     9
#define KC_BLOCKS 250
#define KC_CHUNK  6400       // 250 * 6400 = 1.6M edges
#define LCOL_CAP  10240
#define QW      25000u       // src quartile width

#define GBM 128
#define NBLK_G ((N_NODES + GBM - 1) / GBM)                     // 782

typedef __attribute__((ext_vector_type(8))) short short8v;
typedef __attribute__((ext_vector_type(4))) float f32x4;
typedef __attribute__((ext_vector_type(2))) float f32x2;
typedef __attribute__((ext_vector_type(4))) int int4v;
typedef __attribute__((ext_vector_type(2))) int int2v;

__device__ __forceinline__ float b2f(unsigned short h) {
    return __uint_as_float(((unsigned int)h) << 16);
}
__device__ __forceinline__ unsigned short f2b(float f) {
    unsigned int u = __float_as_uint(f);
    u += 0x7FFF + ((u >> 16) & 1);          // RNE
    return (unsigned short)(u >> 16);
}
__device__ __forceinline__ unsigned char f2f8(float f) {
    unsigned int u = __builtin_amdgcn_cvt_pk_fp8_f32(f, f, 0, false);
    return (unsigned char)(u & 0xff);
}
__device__ __forceinline__ void gl_lds16(const void* g, void* l) {
    __builtin_amdgcn_global_load_lds((const __attribute__((address_space(1))) unsigned int*)g,
                                     (__attribute__((address_space(3))) unsigned int*)l,
                                     16, 0, 0);
}
// 8 fp8 (pre-BN H) -> bn+relu -> 8 bf16
__device__ __forceinline__ short8v bn_pack8(int2v rv8, const float* __restrict__ scsh,
                                            int c0) {
    short8v o;
#pragma unroll
    for (int w = 0; w < 2; ++w) {
        unsigned int u = (unsigned int)rv8[w];
        f32x2 lo = __builtin_amdgcn_cvt_pk_f32_fp8(u, false);
        f32x2 hi = __builtin_amdgcn_cvt_pk_f32_fp8(u, true);
        float f[4] = { lo[0], lo[1], hi[0], hi[1] };
#pragma unroll
        for (int j = 0; j < 4; ++j) {
            int c = c0 + w * 4 + j;
            o[w * 4 + j] = (short)f2b(fmaxf(0.f, f[j] * scsh[c] + scsh[HDIM + c]));
        }
    }
    return o;
}

// ---------------- CSR build v4: bucketed radix, per-node lists sorted by src quartile ----------------

__global__ void __launch_bounds__(256) k_hist(const int* __restrict__ dst,
                                              int* __restrict__ bcnt) {
    __shared__ int h[NBUCK];
    for (int i = threadIdx.x; i < NBUCK; i += 256) h[i] = 0;
    __syncthreads();
    const int4v* d4 = (const int4v*)dst;
    int base = blockIdx.x * (KC_CHUNK / 4);
    for (int i = threadIdx.x; i < KC_CHUNK / 4; i += 256) {
        int4v d = __builtin_nontemporal_load(d4 + base + i);
        atomicAdd(&h[d[0] >> BSH], 1);
        atomicAdd(&h[d[1] >> BSH], 1);
        atomicAdd(&h[d[2] >> BSH], 1);
        atomicAdd(&h[d[3] >> BSH], 1);
    }
    __syncthreads();
    for (int i = threadIdx.x; i < NBUCK; i += 256)
        if (h[i]) atomicAdd(&bcnt[i], h[i]);
}

__global__ void k_bscan(const int* __restrict__ bcnt, int* __restrict__ boff,
                        int* __restrict__ bcur, int* __restrict__ row_off) {
    if (threadIdx.x == 0 && blockIdx.x == 0) {
        int acc = 0;
        for (int i = 0; i < NBUCK; ++i) {
            boff[i] = acc; bcur[i] = acc; acc += bcnt[i];
        }
        boff[NBUCK] = acc;
        row_off[N_NODES] = N_EDGES;
    }
}

__global__ void __launch_bounds__(256) k_part(const int* __restrict__ src,
                                              const int* __restrict__ dst,
                                              int* __restrict__ bcur,
                                              int2v* __restrict__ P) {
    __shared__ int h[NBUCK];
    __shared__ int gbase[NBUCK];
    for (int i = threadIdx.x; i < NBUCK; i += 256) h[i] = 0;
    __syncthreads();
    const int4v* d4 = (const int4v*)dst;
    const int4v* s4 = (const int4v*)src;
    const int base = blockIdx.x * (KC_CHUNK / 4);
    for (int i = threadIdx.x; i < KC_CHUNK / 4; i += 256) {
        int4v d = __builtin_nontemporal_load(d4 + base + i);
        atomicAdd(&h[d[0] >> BSH], 1);
        atomicAdd(&h[d[1] >> BSH], 1);
        atomicAdd(&h[d[2] >> BSH], 1);
        atomicAdd(&h[d[3] >> BSH], 1);
    }
    __syncthreads();
    for (int i = threadIdx.x; i < NBUCK; i += 256) {
        int c = h[i];
        gbase[i] = c ? atomicAdd(&bcur[i], c) : 0;
        h[i] = 0;
    }
    __syncthreads();
    for (int i = threadIdx.x; i < KC_CHUNK / 4; i += 256) {
        int4v d = __builtin_nontemporal_load(d4 + base + i);
        int4v s = __builtin_nontemporal_load(s4 + base + i);
#pragma unroll
        for (int k = 0; k < 4; ++k) {
            int b = d[k] >> BSH;
            int pos = gbase[b] + atomicAdd(&h[b], 1);
            int2v pr; pr[0] = s[k]; pr[1] = d[k];
            P[pos] = pr;
        }
    }
}

__global__ void __launch_bounds__(1024) k_bucket(const int2v* __restrict__ P,
                                                 const int* __restrict__ boff,
                                                 int* __restrict__ row_off,
                                                 int* __restrict__ col) {
    __shared__ int ldeg[2048];
    __shared__ int lcur[2048];
    __shared__ int lcol[LCOL_CAP];
    const int tid = threadIdx.x;
    const int b = blockIdx.x;
    const int pbeg = boff[b], pend = boff[b + 1];
    const int nE = pend - pbeg;
    const int n0 = b << BSH;
    for (int i = tid; i < 2048; i += 1024) ldeg[i] = 0;
    __syncthreads();
    for (int i = tid; i < nE; i += 1024) {
        int2v pr = P[pbeg + i];
        int q = (int)((unsigned)pr[0] / QW);
        atomicAdd(&ldeg[((pr[1] - n0) << 2) + q], 1);
    }
    __syncthreads();
    int a0 = ldeg[2 * tid];
    int a1 = ldeg[2 * tid + 1];
    lcur[tid] = a0 + a1;
    __syncthreads();
    for (int off = 1; off < 1024; off <<= 1) {
        int t = (tid >= off) ? lcur[tid - off] : 0;
        __syncthreads();
        lcur[tid] += t;
        __syncthreads();
    }
    int basex = (tid > 0) ? lcur[tid - 1] : 0;
    __syncthreads();
    ldeg[2 * tid] = basex;
    ldeg[2 * tid + 1] = basex + a0;
    __syncthreads();
    for (int i = tid; i < 2048; i += 1024) lcur[i] = ldeg[i];
    if (tid < 512) {
        int node = n0 + tid;
        if (node < N_NODES) row_off[node] = pbeg + ldeg[tid << 2];
    }
    __syncthreads();
    for (int i = tid; i < nE; i += 1024) {
        int2v pr = P[pbeg + i];
        int q = (int)((unsigned)pr[0] / QW);
        int pos = atomicAdd(&lcur[((pr[1] - n0) << 2) + q], 1);
        if (pos < LCOL_CAP) lcol[pos] = pr[0];
    }
    __syncthreads();
    for (int i = tid; i < nE; i += 1024) col[pbeg + i] = lcol[i];
}

// ---------------- one-time converts ----------------

__global__ void __launch_bounds__(256) k_cvt_x(const float* __restrict__ x,
                                               unsigned short* __restrict__ Xb,
                                               unsigned int* __restrict__ X8) {
    int idx = blockIdx.x * 256 + threadIdx.x;
    f32x4 v = __builtin_nontemporal_load(((const f32x4*)x) + idx);
    ushort4 o = { f2b(v[0]), f2b(v[1]), f2b(v[2]), f2b(v[3]) };
    ((ushort4*)Xb)[idx] = o;
    unsigned int d = 0;
    d = __builtin_amdgcn_cvt_pk_fp8_f32(v[0], v[1], d, false);
    d = __builtin_amdgcn_cvt_pk_fp8_f32(v[2], v[3], d, true);
    X8[idx] = d;
}

__global__ void __launch_bounds__(256) k_cvt_w(const float* __restrict__ Wl,
                                               const float* __restrict__ Wr,
                                               unsigned short* __restrict__ Wtb) {
    int idx = blockIdx.x * 256 + threadIdx.x;
    int kk = idx & 255;
    int n  = (idx >> 8) & 127;
    int l  = idx >> 15;
    float v = (kk < HDIM) ? Wl[l * HDIM * HDIM + kk * HDIM + n]
                          : Wr[l * HDIM * HDIM + (kk - HDIM) * HDIM + n];
    Wtb[idx] = f2b(v);
}

// X8 = fp8(relu(bn(H8)))  (H8 is pre-BN fp8)
__global__ void __launch_bounds__(256) k_bnx8(const unsigned char* __restrict__ H8,
                                              const float* __restrict__ scsh,
                                              int2v* __restrict__ X8) {
    int idx = blockIdx.x * 256 + threadIdx.x;          // 8-channel index, < N*H/8
    int c8 = (idx & 15) * 8;
    int2v v = ((const int2v*)H8)[idx];
    float f[8];
#pragma unroll
    for (int w = 0; w < 2; ++w) {
        unsigned int u = (unsigned int)v[w];
        f32x2 lo = __builtin_amdgcn_cvt_pk_f32_fp8(u, false);
        f32x2 hi = __builtin_amdgcn_cvt_pk_f32_fp8(u, true);
        f[w * 4 + 0] = lo[0]; f[w * 4 + 1] = lo[1];
        f[w * 4 + 2] = hi[0]; f[w * 4 + 3] = hi[1];
    }
#pragma unroll
    for (int j = 0; j < 8; ++j)
        f[j] = fmaxf(0.f, f[j] * scsh[c8 + j] + scsh[HDIM + c8 + j]);
    unsigned int d0 = 0, d1 = 0;
    d0 = __builtin_amdgcn_cvt_pk_fp8_f32(f[0], f[1], d0, false);
    d0 = __builtin_amdgcn_cvt_pk_fp8_f32(f[2], f[3], d0, true);
    d1 = __builtin_amdgcn_cvt_pk_fp8_f32(f[4], f[5], d1, false);
    d1 = __builtin_amdgcn_cvt_pk_fp8_f32(f[6], f[7], d1, true);
    int2v o; o[0] = (int)d0; o[1] = (int)d1;
    X8[idx] = o;
}

// ---------------- fused fp8-gather + GEMM + BN-stat partials ----------------
// 512 thr = 8 waves (2m x 4n), 128 rows/block, LDS 32KB (A dbuf 2x8K | W dbuf 2x8K).
// BN=false (layer 0): root operand Hsrc is bf16 Xb. BN=true: Hsrc is fp8 H8prev,
// bn+relu applied in-register. H output stored as fp8 (stats from exact f32).

template<bool BN>
__global__ void __launch_bounds__(512) k_fused(const unsigned char* __restrict__ X8,
                                               const void* __restrict__ Hsrc,
                                               const float* __restrict__ scsh,
                                               const int* __restrict__ row_off,
                                               const int* __restrict__ col,
                                               const unsigned short* __restrict__ Wtb,
                                               const float* __restrict__ bl,
                                               unsigned char* __restrict__ H8out,
                                               float* __restrict__ pstat) {
    __shared__ __align__(16) char smem[32768];
    __shared__ int sro[129];
    const int tid  = threadIdx.x;
    const int bm   = blockIdx.x * GBM;
    const int wv   = tid >> 6;
    const int lane = tid & 63;
    const int li   = lane & 15, hi = lane >> 4;
    const int wm   = wv & 1, wn = wv >> 1;
    const int rr   = tid >> 2, sk = tid & 3;
    const int swz  = ((sk ^ ((rr >> 1) & 3)) << 4);

    gl_lds16((const char*)(Wtb + (size_t)rr * 256) + swz, smem + 16384 + wv * 1024);

    int* lcol = (int*)smem;
    if (tid <= 128) {
        int ii = bm + tid; if (ii > N_NODES) ii = N_NODES;
        sro[tid] = row_off[ii];
    }
    __syncthreads();
    const int s0 = sro[0];
    const int nEb = sro[128] - s0;
    const bool fits = (nEb <= 4096);
    if (fits) for (int i = tid; i < nEb; i += 512) lcol[i] = col[s0 + i];
    __syncthreads();

    // ---- gather phase: node bm+rr, fp8 channels [32sk, 32sk+32) ----
    const int s = sro[rr] - s0, e = sro[rr + 1] - s0;
    const int* cp = fits ? lcol : (col + s0);
    const int c32 = sk * 32;
    f32x2 a2[16] = {};
    auto accum16 = [&](int4v v, int base) {
#pragma unroll
        for (int q = 0; q < 4; ++q) {
            unsigned int w = (unsigned int)v[q];
            a2[base + 2 * q]     += __builtin_amdgcn_cvt_pk_f32_fp8(w, false);
            a2[base + 2 * q + 1] += __builtin_amdgcn_cvt_pk_f32_fp8(w, true);
        }
    };
    int p = s;
    for (; p + 4 <= e; p += 4) {
        int nbx[4];
#pragma unroll
        for (int j = 0; j < 4; ++j) nbx[j] = cp[p + j];
        int4v v0[4], v1[4];
#pragma unroll
        for (int j = 0; j < 4; ++j) {
            const unsigned char* rowp = X8 + (size_t)nbx[j] * HDIM + c32;
            v0[j] = *(const int4v*)rowp;
            v1[j] = *(const int4v*)(rowp + 16);
        }
#pragma unroll
        for (int j = 0; j < 4; ++j) { accum16(v0[j], 0); accum16(v1[j], 8); }
    }
    for (; p < e; ++p) {
        const unsigned char* rowp = X8 + (size_t)cp[p] * HDIM + c32;
        accum16(*(const int4v*)rowp, 0);
        accum16(*(const int4v*)(rowp + 16), 8);
    }
    const float wgt = (e > s) ? 1.0f / (float)(e - s) : 0.f;
    short8v aggout[4];
#pragma unroll
    for (int j = 0; j < 4; ++j)
#pragma unroll
        for (int t = 0; t < 8; ++t)
            aggout[j][t] = (short)f2b(a2[j * 4 + (t >> 1)][t & 1] * wgt);

    __syncthreads();
    if (sk == 0) {
#pragma unroll
        for (int j = 0; j < 4; ++j)
            *(short8v*)(smem + rr * 64 + ((j ^ ((rr >> 1) & 3)) << 4)) = aggout[j];
    }
    __syncthreads();

    // ---- K-loop ----
    f32x4 acc[4][2] = {};
    int buf = 0;
    for (int step = 0; step < 8; ++step) {
        char* curA = smem + buf * 8192;
        char* curW = smem + 16384 + buf * 8192;
        char* nxtA = smem + (buf ^ 1) * 8192;
        const int ns = step + 1;
        short8v rv16;            // bf16 path (layer 0)
        int2v rv8;               // fp8 path (layers 1+)
        int c0 = 0;
        bool regstage = false;
        if (step < 7) {
            gl_lds16((const char*)(Wtb + (size_t)rr * 256 + ns * 32) + swz,
                     smem + 16384 + (buf ^ 1) * 8192 + wv * 1024);
            if (ns >= 4) {
                regstage = true;
                c0 = (ns - 4) * 32 + sk * 8;
                int row = bm + rr; if (row >= N_NODES) row = N_NODES - 1;
                if (BN) {
                    rv8 = *(const int2v*)((const unsigned char*)Hsrc +
                                          (size_t)row * HDIM + c0);
                } else {
                    rv16 = *(const short8v*)((const unsigned short*)Hsrc +
                                             (size_t)row * HDIM + c0);
                }
            }
        }

        short8v afr[4], bfr[2];
#pragma unroll
        for (int m = 0; m < 4; ++m) {
            int r = wm * 64 + m * 16 + li;
            afr[m] = *(const short8v*)(curA + r * 64 + ((hi ^ ((r >> 1) & 3)) << 4));
        }
#pragma unroll
        for (int nf = 0; nf < 2; ++nf) {
            int n = wn * 32 + nf * 16 + li;
            bfr[nf] = *(const short8v*)(curW + n * 64 + ((hi ^ ((n >> 1) & 3)) << 4));
        }
#pragma unroll
        for (int m = 0; m < 4; ++m)
#pragma unroll
            for (int nf = 0; nf < 2; ++nf)
                acc[m][nf] = __builtin_amdgcn_mfma_f32_16x16x32_bf16(afr[m], bfr[nf],
                                                                     acc[m][nf], 0, 0, 0);

        if (step < 7) {
            if (ns < 4) {
                if (sk == ns) {
#pragma unroll
                    for (int j = 0; j < 4; ++j)
                        *(short8v*)(nxtA + rr * 64 + ((j ^ ((rr >> 1) & 3)) << 4)) = aggout[j];
                }
            } else if (regstage) {
                short8v ov;
                if (BN) ov = bn_pack8(rv8, scsh, c0);
                else    ov = rv16;
                *(short8v*)(nxtA + rr * 64 + swz) = ov;
            }
        }
        __syncthreads();
        buf ^= 1;
    }

    // ---- epilogue: bias, fp8 H write, BN-stat partials (stats from exact f32) ----
    float* st = (float*)smem;
#pragma unroll
    for (int nf = 0; nf < 2; ++nf) {
        int c = wn * 32 + nf * 16 + li;
        float bb = bl[c];
        float ls = 0.f, lq = 0.f;
#pragma unroll
        for (int m = 0; m < 4; ++m) {
            int row0 = bm + wm * 64 + m * 16 + hi * 4;
#pragma unroll
            for (int j = 0; j < 4; ++j) {
                int row = row0 + j;
                if (row < N_NODES) {
                    float v = acc[m][nf][j] + bb;
                    H8out[(size_t)row * HDIM + c] = f2f8(v);
                    ls += v; lq += v * v;
                }
            }
        }
        ls += __shfl_xor(ls, 16); ls += __shfl_xor(ls, 32);
        lq += __shfl_xor(lq, 16); lq += __shfl_xor(lq, 32);
        if (hi == 0) {
            st[wv * 128 + c] = ls;
            st[1024 + wv * 128 + c] = lq;
        }
    }
    __syncthreads();
    if (tid < 128) {
        int w0 = (tid >> 5) * 2;
        float s2 = st[w0 * 128 + tid] + st[(w0 + 1) * 128 + tid];
        pstat[blockIdx.x * 256 + tid] = s2;
    } else if (tid < 256) {
        int c = tid - 128;
        int w0 = (c >> 5) * 2;
        float q = st[1024 + w0 * 128 + c] + st[1024 + (w0 + 1) * 128 + c];
        pstat[blockIdx.x * 256 + tid] = q;
    }
}

// ---------------- BN stats reduction (2 dispatches, parallel) ----------------

__global__ void __launch_bounds__(256) k_red1(const float* __restrict__ pstat,
                                              float* __restrict__ red32) {
    int c = threadIdx.x, b = blockIdx.x;
    float s = 0.f;
    for (int r = b; r < NBLK_G; r += 32) s += pstat[r * 256 + c];
    red32[b * 256 + c] = s;
}

__global__ void __launch_bounds__(128) k_stats_final(const float* __restrict__ red32,
                                                     const float* __restrict__ gamma,
                                                     const float* __restrict__ beta,
                                                     float* __restrict__ scsh) {
    int c = threadIdx.x;
    float s = 0.f, q = 0.f;
    for (int r = 0; r < 32; ++r) { s += red32[r * 256 + c]; q += red32[r * 256 + 128 + c]; }
    float mu = s / (float)N_NODES;
    float var = q / (float)N_NODES - mu * mu;
    float rs = rsqrtf(var + BN_EPS);
    float sc = gamma[c] * rs;
    scsh[c] = sc;
    scsh[HDIM + c] = beta[c] - mu * sc;
}

// ---------------- pooling + classifier ----------------

__global__ void k_gbound(const int* __restrict__ batch, int* __restrict__ gb) {
    int t = blockIdx.x * 64 + threadIdx.x;
    if (t > NGRAPH) return;
    int lo = 0, hi = N_NODES;
    while (lo < hi) { int mid = (lo + hi) >> 1; if (batch[mid] < t) lo = mid + 1; else hi = mid; }
    gb[t] = lo;
}

// pool over bn_relu(H8 final) applied on the fly
__global__ void __launch_bounds__(128) k_pool_part(const unsigned char* __restrict__ H8,
                                                   const float* __restrict__ scsh,
                                                   const int* __restrict__ gb,
                                                   float* __restrict__ ppart) {
    int g = blockIdx.x, sp = blockIdx.y;
    int c = threadIdx.x;
    float sc = scsh[c], sh = scsh[HDIM + c];
    int s = gb[g], e = gb[g + 1];
    float acc = 0.f;
    for (int i = s + sp; i < e; i += POOL_SPLIT) {
        unsigned int u = (unsigned int)H8[(size_t)i * HDIM + c];
        f32x2 t = __builtin_amdgcn_cvt_pk_f32_fp8(u, false);
        acc += fmaxf(0.f, t[0] * sc + sh);
    }
    ppart[(g * POOL_SPLIT + sp) * HDIM + c] = acc;
}

__global__ void __launch_bounds__(128) k_pool_final(const int* __restrict__ gb,
                                                    const float* __restrict__ ppart,
                                                    float* __restrict__ pooled) {
    int g = blockIdx.x, c = threadIdx.x;
    float s = 0.f;
    for (int sp = 0; sp < POOL_SPLIT; ++sp) s += ppart[(g * POOL_SPLIT + sp) * HDIM + c];
    int cnt = gb[g + 1] - gb[g]; if (cnt < 1) cnt = 1;
    pooled[g * HDIM + c] = s / (float)cnt;
}

__global__ void __launch_bounds__(128) k_lin(const float* __restrict__ pooled,
                                             const float* __restrict__ W,
                                             const float* __restrict__ bvec,
                                             float* __restrict__ out) {
    __shared__ float p[HDIM];
    int g = blockIdx.x, t = threadIdx.x;
    p[t] = pooled[g * HDIM + t];
    __syncthreads();
    if (t < NCLASS) {
        float acc = bvec[t];
        for (int k = 0; k < HDIM; ++k) acc += p[k] * W[k * NCLASS + t];
        out[g * NCLASS + t] = acc;
    }
}

// ---------------- launch ----------------

extern "C" void kernel_launch(void* const* d_in, const int* in_sizes, int n_in,
                              void* d_out, int out_size, void* d_ws, size_t ws_size,
                              hipStream_t stream) {
    const float* x     = (const float*)d_in[0];
    const int*   eidx  = (const int*)d_in[1];
    const int*   batch = (const int*)d_in[2];
    const float* Wl    = (const float*)d_in[3];
    const float* bl    = (const float*)d_in[4];
    const float* Wr    = (const float*)d_in[5];
    const float* gamma = (const float*)d_in[6];
    const float* beta  = (const float*)d_in[7];
    const float* linW  = (const float*)d_in[8];
    const float* linb  = (const float*)d_in[9];
    float* out = (float*)d_out;

    const int* src = eidx;
    const int* dst = eidx + N_EDGES;

    char* p = (char*)d_ws;
    auto alloc = [&](size_t bytes) { char* r = p; p += (bytes + 255) & ~(size_t)255; return r; };
    unsigned short* Xb   = (unsigned short*)alloc((size_t)N_NODES * HDIM * 2);
    unsigned char*  X8   = (unsigned char*)alloc((size_t)N_NODES * HDIM);
    unsigned char*  H8A  = (unsigned char*)alloc((size_t)N_NODES * HDIM);
    unsigned char*  H8B  = (unsigned char*)alloc((size_t)N_NODES * HDIM);
    unsigned short* Wtb  = (unsigned short*)alloc((size_t)NLAYER * 2 * HDIM * HDIM * 2);
    int*   row_off = (int*)alloc((N_NODES + 2) * 4);
    int*   col     = (int*)alloc((size_t)N_EDGES * 4);
    int2v* P       = (int2v*)alloc((size_t)N_EDGES * 8);
    int*   bcnt    = (int*)alloc(NBUCK * 4);
    int*   boff    = (int*)alloc((NBUCK + 1) * 4);
    int*   bcur    = (int*)alloc(NBUCK * 4);
    int*   gb      = (int*)alloc((NGRAPH + 2) * 4);
    float* pstat   = (float*)alloc((size_t)NBLK_G * 256 * 4);
    float* red32   = (float*)alloc(32 * 256 * 4);
    float* scsh    = (float*)alloc(2 * HDIM * 4);
    float* ppart   = (float*)alloc((size_t)NGRAPH * POOL_SPLIT * HDIM * 4);
    float* pooled  = (float*)alloc(NGRAPH * HDIM * 4);

    // ---- CSR build v4 ----
    hipMemsetAsync(bcnt, 0, NBUCK * sizeof(int), stream);
    k_hist<<<KC_BLOCKS, 256, 0, stream>>>(dst, bcnt);
    k_bscan<<<1, 64, 0, stream>>>(bcnt, boff, bcur, row_off);
    k_part<<<KC_BLOCKS, 256, 0, stream>>>(src, dst, bcur, P);
    k_bucket<<<NBUCK, 1024, 0, stream>>>(P, boff, row_off, col);

    // ---- one-time converts ----
    k_cvt_x<<<N_NODES * HDIM / 4 / 256, 256, 0, stream>>>(x, Xb, (unsigned int*)X8);
    k_cvt_w<<<NLAYER * 2 * HDIM * HDIM / 256, 256, 0, stream>>>(Wl, Wr, Wtb);
    k_gbound<<<3, 64, 0, stream>>>(batch, gb);

    // ---- layer 0 (root operand = bf16 Xb) ----
    k_fused<false><<<NBLK_G, 512, 0, stream>>>(X8, Xb, scsh, row_off, col,
                                               Wtb, bl, H8A, pstat);
    k_red1<<<32, 256, 0, stream>>>(pstat, red32);
    k_stats_final<<<1, 128, 0, stream>>>(red32, gamma, beta, scsh);

    // ---- layers 1..5 (root operand = fp8 H8prev + in-register BN) ----
    unsigned char* Hcur = H8A;
    for (int l = 1; l < NLAYER; ++l) {
        unsigned char* Hout = (l & 1) ? H8B : H8A;
        k_bnx8<<<N_NODES * HDIM / 8 / 256, 256, 0, stream>>>(Hcur, scsh, (int2v*)X8);
        k_fused<true><<<NBLK_G, 512, 0, stream>>>(
            X8, Hcur, scsh, row_off, col, Wtb + (size_t)l * 2 * HDIM * HDIM,
            bl + (size_t)l * HDIM, Hout, pstat);
        k_red1<<<32, 256, 0, stream>>>(pstat, red32);
        k_stats_final<<<1, 128, 0, stream>>>(red32, gamma + (size_t)l * HDIM,
                                             beta + (size_t)l * HDIM, scsh);
        Hcur = Hout;
    }

    // ---- pool + classifier ----
    k_pool_part<<<dim3(NGRAPH, POOL_SPLIT), 128, 0, stream>>>(Hcur, scsh, gb, ppart);
    k_pool_final<<<NGRAPH, 128, 0, stream>>>(gb, ppart, pooled);
    k_lin<<<NGRAPH, 128, 0, stream>>>(pooled, linW, linb, out);
}